// Round 1
// 493.487 us; speedup vs baseline: 1.1899x; 1.1899x over previous
//
#include <hip/hip_runtime.h>
#include <stdint.h>

#define NT 4096     // tokens
#define HD 1024     // hidden
#define ID 512      // intermediate
#define RE 32       // routed experts
#define EE 40       // total experts
#define KT 4        // top-k
#define CAPACITY 768

typedef __bf16 bf16x8 __attribute__((ext_vector_type(8)));
typedef float f32x4 __attribute__((ext_vector_type(4)));
typedef unsigned int u32x4 __attribute__((ext_vector_type(4)));
typedef unsigned int u32x2 __attribute__((ext_vector_type(2)));
typedef unsigned short u16x4 __attribute__((ext_vector_type(4)));

__device__ __forceinline__ float bf2f(unsigned short u) {
    union { unsigned int i; float f; } v; v.i = ((unsigned int)u) << 16; return v.f;
}
__device__ __forceinline__ unsigned short f2bf(float f) {
    union { float f; unsigned int i; } v; v.f = f;
    unsigned int u = v.i;
    return (unsigned short)((u + 0x7fffu + ((u >> 16) & 1u)) >> 16);
}

// Load 8 contiguous logical elements [ei..ei+8) as packed bf16 (u32x4).
__device__ __forceinline__ u32x4 ld8(const void* p, size_t ei, int inF32) {
    if (!inF32) {
        return *(const u32x4*)((const unsigned short*)p + ei);
    } else {
        const float* f = (const float*)p + ei;
        f32x4 a = *(const f32x4*)f;
        f32x4 b = *(const f32x4*)(f + 4);
        u32x4 r;
        r[0] = (unsigned)f2bf(a[0]) | ((unsigned)f2bf(a[1]) << 16);
        r[1] = (unsigned)f2bf(a[2]) | ((unsigned)f2bf(a[3]) << 16);
        r[2] = (unsigned)f2bf(b[0]) | ((unsigned)f2bf(b[1]) << 16);
        r[3] = (unsigned)f2bf(b[2]) | ((unsigned)f2bf(b[3]) << 16);
        return r;
    }
}

// global -> LDS direct staging, 16B per lane. LDS dest is wave-uniform base + lane*16.
typedef __attribute__((address_space(1))) const unsigned int gas_u32;
typedef __attribute__((address_space(3))) unsigned int las_u32;
#define GLL(g, l) __builtin_amdgcn_global_load_lds((gas_u32*)(g), (las_u32*)(l), 16, 0, 0)

// ---------------- dtype detection ----------------
__global__ __launch_bounds__(256) void detect_k(const void* __restrict__ X,
                                                const void* __restrict__ idx,
                                                int* __restrict__ flags) {
    __shared__ int sInsane, sOddNZ;
    const int tid = threadIdx.x;
    if (tid == 0) { sInsane = 0; sOddNZ = 0; }
    __syncthreads();
    const unsigned short* xu = (const unsigned short*)X;
    int cnt = 0;
    for (int i = tid; i < 8192; i += 256) {
        int e = (xu[i] >> 7) & 0xFF;
        if (e >= 0x90) cnt++;
    }
    if (cnt) atomicAdd(&sInsane, cnt);
    const int* ip = (const int*)idx;
    int odd = 0;
    for (int i = tid; i < 512; i += 256)
        if ((i & 1) && ip[i] != 0) odd++;
    if (odd) atomicAdd(&sOddNZ, odd);
    __syncthreads();
    if (tid == 0) {
        flags[0] = (sInsane > 64) ? 1 : 0;
        flags[1] = (sOddNZ == 0) ? 1 : 0;
    }
}

// ---------------- routing ----------------
__global__ __launch_bounds__(256) void route_k(const int* __restrict__ idx,
                                               const int* __restrict__ flags,
                                               int* __restrict__ cnt,
                                               int* __restrict__ tok,
                                               int* __restrict__ smap) {
    int a = blockIdx.x * 256 + threadIdx.x;
    if (a >= NT * KT) return;
    const int isI64 = flags[1];
    int e = isI64 ? idx[a << 1] : idx[a];
    int s = -1;
    if (e < RE) {
        int slot = atomicAdd(&cnt[e], 1);
        if (slot < CAPACITY) {
            tok[e * CAPACITY + slot] = a >> 2;
            s = slot;
        }
    }
    smap[a] = s;
}

// ---------------- convert: X/W1(routed)/W2 -> packed bf16 workspace ----------------
__global__ __launch_bounds__(256) void convert_k(
    const void* __restrict__ X, const void* __restrict__ W1, const void* __restrict__ W2,
    const int* __restrict__ flags,
    unsigned short* __restrict__ Xb, unsigned short* __restrict__ W1b,
    unsigned short* __restrict__ W2b)
{
    const int inF32 = flags[0];
    const size_t gid = (size_t)blockIdx.x * 256 + threadIdx.x;
    const size_t stride = (size_t)gridDim.x * 256;
    const size_t nx = (size_t)NT * HD / 4;
    const size_t n1 = (size_t)RE * 2 * ID * HD / 4;
    const size_t n2 = (size_t)RE * HD * ID / 4;
    if (inF32) {
        for (size_t i = gid; i < nx; i += stride) {
            f32x4 v = ((const f32x4*)X)[i];
            u32x2 r; r[0] = (unsigned)f2bf(v[0]) | ((unsigned)f2bf(v[1]) << 16);
            r[1] = (unsigned)f2bf(v[2]) | ((unsigned)f2bf(v[3]) << 16);
            ((u32x2*)Xb)[i] = r;
        }
        for (size_t i = gid; i < n1; i += stride) {
            f32x4 v = ((const f32x4*)W1)[i];
            u32x2 r; r[0] = (unsigned)f2bf(v[0]) | ((unsigned)f2bf(v[1]) << 16);
            r[1] = (unsigned)f2bf(v[2]) | ((unsigned)f2bf(v[3]) << 16);
            ((u32x2*)W1b)[i] = r;
        }
        for (size_t i = gid; i < n2; i += stride) {
            f32x4 v = ((const f32x4*)W2)[i];
            u32x2 r; r[0] = (unsigned)f2bf(v[0]) | ((unsigned)f2bf(v[1]) << 16);
            r[1] = (unsigned)f2bf(v[2]) | ((unsigned)f2bf(v[3]) << 16);
            ((u32x2*)W2b)[i] = r;
        }
    } else {
        for (size_t i = gid; i < nx; i += stride) ((u32x2*)Xb)[i] = ((const u32x2*)X)[i];
        for (size_t i = gid; i < n1; i += stride) ((u32x2*)W1b)[i] = ((const u32x2*)W1)[i];
        for (size_t i = gid; i < n2; i += stride) ((u32x2*)W2b)[i] = ((const u32x2*)W2)[i];
    }
}

// ---------------- GEMM1 (bf16, global_load_lds staging) ----------------
// grid: (6 mtiles, 4 ntiles over I, 32 experts); block 256 = 4 waves (2x2 of 64x64)
__global__ __launch_bounds__(256, 2) void gemm1n_k(
    const unsigned short* __restrict__ Xb,   // [NT][HD] bf16
    const unsigned short* __restrict__ W1b,  // [RE][2*ID][HD] bf16
    const int* __restrict__ cnts,
    const int* __restrict__ tok,
    unsigned short* __restrict__ mid)        // [RE][CAPACITY][ID] bf16
{
    const int e = blockIdx.z;
    int cnt = cnts[e]; if (cnt > CAPACITY) cnt = CAPACITY;
    const int m0 = blockIdx.x * 128;
    if (m0 >= cnt) return;
    const int n0 = blockIdx.y * 128;

    __shared__ unsigned short Ash[4 * 128 * 8];  // 8 KB, elem (kc*128+row)*8
    __shared__ unsigned short Bgs[4 * 128 * 8];
    __shared__ unsigned short Bus[4 * 128 * 8];

    const int tid  = threadIdx.x;
    const int lane = tid & 63;
    const int wv   = tid >> 6;            // wave handles K-chunk kc = wv
    const int wm   = wv >> 1, wn = wv & 1;
    const int q    = lane >> 4, ln = lane & 15;

    // per-lane global sources (gathered A rows are legal: global src is per-lane)
    const int r0 = m0 + lane, r1 = m0 + 64 + lane;
    const int t0 = (r0 < cnt) ? tok[e * CAPACITY + r0] : 0;
    const int t1 = (r1 < cnt) ? tok[e * CAPACITY + r1] : 0;
    const unsigned short* gA0 = Xb + (size_t)t0 * HD + wv * 8;
    const unsigned short* gA1 = Xb + (size_t)t1 * HD + wv * 8;
    const unsigned short* gG0 = W1b + ((size_t)e * 1024 + n0 + lane) * HD + wv * 8;
    const unsigned short* gG1 = gG0 + (size_t)64 * HD;
    const unsigned short* gU0 = W1b + ((size_t)e * 1024 + 512 + n0 + lane) * HD + wv * 8;
    const unsigned short* gU1 = gU0 + (size_t)64 * HD;
    // wave-uniform LDS dests (lane writes base + lane*16B)
    unsigned short* lA0 = &Ash[(wv * 128 + 0) * 8];
    unsigned short* lA1 = &Ash[(wv * 128 + 64) * 8];
    unsigned short* lG0 = &Bgs[(wv * 128 + 0) * 8];
    unsigned short* lG1 = &Bgs[(wv * 128 + 64) * 8];
    unsigned short* lU0 = &Bus[(wv * 128 + 0) * 8];
    unsigned short* lU1 = &Bus[(wv * 128 + 64) * 8];

    f32x4 accg[4][4], accu[4][4];
    const f32x4 z4 = {0.f, 0.f, 0.f, 0.f};
    #pragma unroll
    for (int a_ = 0; a_ < 4; a_++)
        #pragma unroll
        for (int b_ = 0; b_ < 4; b_++) { accg[a_][b_] = z4; accu[a_][b_] = z4; }

    #define STAGE1(k0) do { \
        GLL(gA0 + (k0), lA0); GLL(gA1 + (k0), lA1); \
        GLL(gG0 + (k0), lG0); GLL(gG1 + (k0), lG1); \
        GLL(gU0 + (k0), lU0); GLL(gU1 + (k0), lU1); } while (0)

    STAGE1(0);
    for (int k0 = 0; k0 < HD; k0 += 32) {
        __syncthreads();   // drains vmcnt -> staged tile visible
        bf16x8 af[4], bgf[4], buf2[4];
        #pragma unroll
        for (int mt = 0; mt < 4; mt++)
            af[mt] = *(const bf16x8*)&Ash[(q * 128 + wm * 64 + mt * 16 + ln) * 8];
        #pragma unroll
        for (int nt = 0; nt < 4; nt++) {
            bgf[nt]  = *(const bf16x8*)&Bgs[(q * 128 + wn * 64 + nt * 16 + ln) * 8];
            buf2[nt] = *(const bf16x8*)&Bus[(q * 128 + wn * 64 + nt * 16 + ln) * 8];
        }
        __syncthreads();   // all reads done before overwrite
        if (k0 + 32 < HD) STAGE1(k0 + 32);
        #pragma unroll
        for (int mt = 0; mt < 4; mt++)
            #pragma unroll
            for (int nt = 0; nt < 4; nt++) {
                accg[mt][nt] = __builtin_amdgcn_mfma_f32_16x16x32_bf16(af[mt], bgf[nt],  accg[mt][nt], 0, 0, 0);
                accu[mt][nt] = __builtin_amdgcn_mfma_f32_16x16x32_bf16(af[mt], buf2[nt], accu[mt][nt], 0, 0, 0);
            }
    }
    #undef STAGE1

    const size_t midBase = (size_t)e * CAPACITY;
    #pragma unroll
    for (int mt = 0; mt < 4; mt++) {
        #pragma unroll
        for (int r = 0; r < 4; r++) {
            int slot = m0 + wm * 64 + mt * 16 + q * 4 + r;
            if (slot < cnt) {
                unsigned short* dst = mid + (midBase + slot) * ID;
                #pragma unroll
                for (int nt = 0; nt < 4; nt++) {
                    int i_col = n0 + wn * 64 + nt * 16 + ln;
                    float gv = accg[mt][nt][r];
                    float uv = accu[mt][nt][r];
                    float sv = gv / (1.f + __expf(-gv));
                    dst[i_col] = f2bf(sv * uv);
                }
            }
        }
    }
}

// ---------------- GEMM2 (bf16, global_load_lds staging) ----------------
// grid: (6 mtiles, 8 ntiles over H, 32 experts)
__global__ __launch_bounds__(256, 2) void gemm2n_k(
    const unsigned short* __restrict__ mid,  // [RE][CAPACITY][ID] bf16
    const unsigned short* __restrict__ W2b,  // [RE][HD][ID] bf16
    const int* __restrict__ cnts,
    unsigned short* __restrict__ ybuf)       // [RE][CAPACITY][HD] bf16
{
    const int e = blockIdx.z;
    int cnt = cnts[e]; if (cnt > CAPACITY) cnt = CAPACITY;
    const int m0 = blockIdx.x * 128;
    if (m0 >= cnt) return;
    const int n0 = blockIdx.y * 128;

    __shared__ unsigned short Ash[4 * 128 * 8];
    __shared__ unsigned short Bsh[4 * 128 * 8];

    const int tid  = threadIdx.x;
    const int lane = tid & 63;
    const int wv   = tid >> 6;
    const int wm   = wv >> 1, wn = wv & 1;
    const int q    = lane >> 4, ln = lane & 15;

    const unsigned short* gA0 = mid + ((size_t)e * CAPACITY + m0 + lane) * ID + wv * 8;
    const unsigned short* gA1 = gA0 + (size_t)64 * ID;
    const unsigned short* gB0 = W2b + ((size_t)e * HD + n0 + lane) * ID + wv * 8;
    const unsigned short* gB1 = gB0 + (size_t)64 * ID;
    unsigned short* lA0 = &Ash[(wv * 128 + 0) * 8];
    unsigned short* lA1 = &Ash[(wv * 128 + 64) * 8];
    unsigned short* lB0 = &Bsh[(wv * 128 + 0) * 8];
    unsigned short* lB1 = &Bsh[(wv * 128 + 64) * 8];

    f32x4 acc[4][4];
    const f32x4 z4 = {0.f, 0.f, 0.f, 0.f};
    #pragma unroll
    for (int a_ = 0; a_ < 4; a_++)
        #pragma unroll
        for (int b_ = 0; b_ < 4; b_++) acc[a_][b_] = z4;

    #define STAGE2(k0) do { \
        GLL(gA0 + (k0), lA0); GLL(gA1 + (k0), lA1); \
        GLL(gB0 + (k0), lB0); GLL(gB1 + (k0), lB1); } while (0)

    STAGE2(0);
    for (int k0 = 0; k0 < ID; k0 += 32) {
        __syncthreads();
        bf16x8 af[4], bf[4];
        #pragma unroll
        for (int mt = 0; mt < 4; mt++)
            af[mt] = *(const bf16x8*)&Ash[(q * 128 + wm * 64 + mt * 16 + ln) * 8];
        #pragma unroll
        for (int nt = 0; nt < 4; nt++)
            bf[nt] = *(const bf16x8*)&Bsh[(q * 128 + wn * 64 + nt * 16 + ln) * 8];
        __syncthreads();
        if (k0 + 32 < ID) STAGE2(k0 + 32);
        #pragma unroll
        for (int mt = 0; mt < 4; mt++)
            #pragma unroll
            for (int nt = 0; nt < 4; nt++)
                acc[mt][nt] = __builtin_amdgcn_mfma_f32_16x16x32_bf16(af[mt], bf[nt], acc[mt][nt], 0, 0, 0);
    }
    #undef STAGE2

    const size_t yBase = (size_t)e * CAPACITY;
    #pragma unroll
    for (int mt = 0; mt < 4; mt++) {
        #pragma unroll
        for (int r = 0; r < 4; r++) {
            int slot = m0 + wm * 64 + mt * 16 + q * 4 + r;
            if (slot < cnt) {
                unsigned short* dst = ybuf + (yBase + slot) * HD;
                #pragma unroll
                for (int nt = 0; nt < 4; nt++) {
                    int h = n0 + wn * 64 + nt * 16 + ln;
                    dst[h] = f2bf(acc[mt][nt][r]);
                }
            }
        }
    }
}

// ---------------- OLD f32-path GEMMs (fallback when workspace is small) ----------------
__global__ __launch_bounds__(256, 2) void gemm1_k(
    const void* __restrict__ X, const void* __restrict__ W1,
    const int* __restrict__ flags, const int* __restrict__ cnts,
    const int* __restrict__ tok, unsigned short* __restrict__ mid)
{
    const int e = blockIdx.z;
    int cnt = cnts[e]; if (cnt > CAPACITY) cnt = CAPACITY;
    const int m0 = blockIdx.x * 128;
    if (m0 >= cnt) return;
    const int n0 = blockIdx.y * 128;
    const int inF32 = flags[0];

    __shared__ unsigned short Ash[4 * 128 * 8];
    __shared__ unsigned short Bgs[4 * 128 * 8];
    __shared__ unsigned short Bus[4 * 128 * 8];

    const int tid  = threadIdx.x;
    const int lane = tid & 63;
    const int wv   = tid >> 6;
    const int wm   = wv >> 1, wn = wv & 1;
    const int q    = lane >> 4, ln = lane & 15;
    const int row = tid & 127;
    const int kcb = tid >> 7;

    const int trow = (m0 + row < cnt) ? tok[e * CAPACITY + m0 + row] : 0;
    const size_t aOff = (size_t)trow * HD;
    const size_t gOff = ((size_t)e * 2 * ID + (n0 + row)) * HD;
    const size_t uOff = ((size_t)e * 2 * ID + (ID + n0 + row)) * HD;

    f32x4 accg[4][4], accu[4][4];
    const f32x4 z4 = {0.f, 0.f, 0.f, 0.f};
    #pragma unroll
    for (int a_ = 0; a_ < 4; a_++)
        #pragma unroll
        for (int b_ = 0; b_ < 4; b_++) { accg[a_][b_] = z4; accu[a_][b_] = z4; }

    u32x4 va[2], vg[2], vu[2];
    #pragma unroll
    for (int i = 0; i < 2; i++) {
        int kc = kcb + 2 * i;
        va[i] = ld8(X,  aOff + kc * 8, inF32);
        vg[i] = ld8(W1, gOff + kc * 8, inF32);
        vu[i] = ld8(W1, uOff + kc * 8, inF32);
    }

    for (int k0 = 0; k0 < HD; k0 += 32) {
        __syncthreads();
        #pragma unroll
        for (int i = 0; i < 2; i++) {
            int kc = kcb + 2 * i;
            *(u32x4*)&Ash[(kc * 128 + row) * 8] = va[i];
            *(u32x4*)&Bgs[(kc * 128 + row) * 8] = vg[i];
            *(u32x4*)&Bus[(kc * 128 + row) * 8] = vu[i];
        }
        __syncthreads();
        if (k0 + 32 < HD) {
            #pragma unroll
            for (int i = 0; i < 2; i++) {
                int kc = kcb + 2 * i;
                va[i] = ld8(X,  aOff + k0 + 32 + kc * 8, inF32);
                vg[i] = ld8(W1, gOff + k0 + 32 + kc * 8, inF32);
                vu[i] = ld8(W1, uOff + k0 + 32 + kc * 8, inF32);
            }
        }
        bf16x8 af[4], bgf[4], buf2[4];
        #pragma unroll
        for (int mt = 0; mt < 4; mt++)
            af[mt] = *(const bf16x8*)&Ash[(q * 128 + wm * 64 + mt * 16 + ln) * 8];
        #pragma unroll
        for (int nt = 0; nt < 4; nt++) {
            bgf[nt]  = *(const bf16x8*)&Bgs[(q * 128 + wn * 64 + nt * 16 + ln) * 8];
            buf2[nt] = *(const bf16x8*)&Bus[(q * 128 + wn * 64 + nt * 16 + ln) * 8];
        }
        #pragma unroll
        for (int mt = 0; mt < 4; mt++)
            #pragma unroll
            for (int nt = 0; nt < 4; nt++) {
                accg[mt][nt] = __builtin_amdgcn_mfma_f32_16x16x32_bf16(af[mt], bgf[nt],  accg[mt][nt], 0, 0, 0);
                accu[mt][nt] = __builtin_amdgcn_mfma_f32_16x16x32_bf16(af[mt], buf2[nt], accu[mt][nt], 0, 0, 0);
            }
    }

    const size_t midBase = (size_t)e * CAPACITY;
    #pragma unroll
    for (int mt = 0; mt < 4; mt++) {
        #pragma unroll
        for (int r = 0; r < 4; r++) {
            int slot = m0 + wm * 64 + mt * 16 + q * 4 + r;
            if (slot < cnt) {
                unsigned short* dst = mid + (midBase + slot) * ID;
                #pragma unroll
                for (int nt = 0; nt < 4; nt++) {
                    int i_col = n0 + wn * 64 + nt * 16 + ln;
                    float gv = accg[mt][nt][r];
                    float uv = accu[mt][nt][r];
                    float sv = gv / (1.f + __expf(-gv));
                    dst[i_col] = f2bf(sv * uv);
                }
            }
        }
    }
}

__global__ __launch_bounds__(256, 2) void gemm2_k(
    const unsigned short* __restrict__ mid, const void* __restrict__ W2,
    const int* __restrict__ flags, const int* __restrict__ cnts,
    unsigned short* __restrict__ ybuf)
{
    const int e = blockIdx.z;
    int cnt = cnts[e]; if (cnt > CAPACITY) cnt = CAPACITY;
    const int m0 = blockIdx.x * 128;
    if (m0 >= cnt) return;
    const int n0 = blockIdx.y * 128;
    const int inF32 = flags[0];

    __shared__ unsigned short Ash[4 * 128 * 8];
    __shared__ unsigned short Bsh[4 * 128 * 8];

    const int tid  = threadIdx.x;
    const int lane = tid & 63;
    const int wv   = tid >> 6;
    const int wm   = wv >> 1, wn = wv & 1;
    const int q    = lane >> 4, ln = lane & 15;
    const int row = tid & 127;
    const int kcb = tid >> 7;

    const unsigned short* aBase = mid + ((size_t)e * CAPACITY + m0 + row) * ID;
    const size_t bOff = ((size_t)e * HD + n0 + row) * ID;

    f32x4 acc[4][4];
    const f32x4 z4 = {0.f, 0.f, 0.f, 0.f};
    #pragma unroll
    for (int a_ = 0; a_ < 4; a_++)
        #pragma unroll
        for (int b_ = 0; b_ < 4; b_++) acc[a_][b_] = z4;

    u32x4 va[2], vb[2];
    #pragma unroll
    for (int i = 0; i < 2; i++) {
        int kc = kcb + 2 * i;
        va[i] = *(const u32x4*)(aBase + kc * 8);
        vb[i] = ld8(W2, bOff + kc * 8, inF32);
    }

    for (int k0 = 0; k0 < ID; k0 += 32) {
        __syncthreads();
        #pragma unroll
        for (int i = 0; i < 2; i++) {
            int kc = kcb + 2 * i;
            *(u32x4*)&Ash[(kc * 128 + row) * 8] = va[i];
            *(u32x4*)&Bsh[(kc * 128 + row) * 8] = vb[i];
        }
        __syncthreads();
        if (k0 + 32 < ID) {
            #pragma unroll
            for (int i = 0; i < 2; i++) {
                int kc = kcb + 2 * i;
                va[i] = *(const u32x4*)(aBase + k0 + 32 + kc * 8);
                vb[i] = ld8(W2, bOff + k0 + 32 + kc * 8, inF32);
            }
        }
        bf16x8 af[4], bf[4];
        #pragma unroll
        for (int mt = 0; mt < 4; mt++)
            af[mt] = *(const bf16x8*)&Ash[(q * 128 + wm * 64 + mt * 16 + ln) * 8];
        #pragma unroll
        for (int nt = 0; nt < 4; nt++)
            bf[nt] = *(const bf16x8*)&Bsh[(q * 128 + wn * 64 + nt * 16 + ln) * 8];
        #pragma unroll
        for (int mt = 0; mt < 4; mt++)
            #pragma unroll
            for (int nt = 0; nt < 4; nt++)
                acc[mt][nt] = __builtin_amdgcn_mfma_f32_16x16x32_bf16(af[mt], bf[nt], acc[mt][nt], 0, 0, 0);
    }

    const size_t yBase = (size_t)e * CAPACITY;
    #pragma unroll
    for (int mt = 0; mt < 4; mt++) {
        #pragma unroll
        for (int r = 0; r < 4; r++) {
            int slot = m0 + wm * 64 + mt * 16 + q * 4 + r;
            if (slot < cnt) {
                unsigned short* dst = ybuf + (yBase + slot) * HD;
                #pragma unroll
                for (int nt = 0; nt < 4; nt++) {
                    int h = n0 + wn * 64 + nt * 16 + ln;
                    dst[h] = f2bf(acc[mt][nt][r]);
                }
            }
        }
    }
}

// ---------------- gather ----------------
__global__ __launch_bounds__(256) void gather_k(
    const void* __restrict__ X,
    const int* __restrict__ idx,
    const void* __restrict__ wts,
    const int* __restrict__ flags,
    const int* __restrict__ smap,
    const unsigned short* __restrict__ ybuf,
    float* __restrict__ out)
{
    const int t = blockIdx.x;
    const int tid = threadIdx.x;
    const int inF32 = flags[0];
    __shared__ int se[KT];
    __shared__ float sw[KT];
    __shared__ int ss[KT];
    if (tid < KT) {
        const int isI64 = flags[1];
        int a = t * KT + tid;
        se[tid] = isI64 ? idx[a << 1] : idx[a];
        sw[tid] = inF32 ? ((const float*)wts)[a] : bf2f(((const unsigned short*)wts)[a]);
        ss[tid] = smap[a];
    }
    __syncthreads();

    const int h = tid * 4;
    float x0, x1, x2, x3;
    if (inF32) {
        f32x4 xv = *(const f32x4*)((const float*)X + (size_t)t * HD + h);
        x0 = xv[0]; x1 = xv[1]; x2 = xv[2]; x3 = xv[3];
    } else {
        u16x4 xv = *(const u16x4*)((const unsigned short*)X + (size_t)t * HD + h);
        x0 = bf2f(xv[0]); x1 = bf2f(xv[1]); x2 = bf2f(xv[2]); x3 = bf2f(xv[3]);
    }
    float zw = 0.f;
    #pragma unroll
    for (int k = 0; k < KT; k++)
        if (se[k] >= RE) zw += sw[k];

    float a0 = zw * x0, a1 = zw * x1, a2 = zw * x2, a3 = zw * x3;

    #pragma unroll
    for (int k = 0; k < KT; k++) {
        if (se[k] < RE && ss[k] >= 0) {
            u16x4 yv = *(const u16x4*)&ybuf[((size_t)se[k] * CAPACITY + ss[k]) * HD + h];
            float w = sw[k];
            a0 += w * bf2f(yv[0]);
            a1 += w * bf2f(yv[1]);
            a2 += w * bf2f(yv[2]);
            a3 += w * bf2f(yv[3]);
        }
    }
    f32x4 o = {a0, a1, a2, a3};
    *(f32x4*)&out[(size_t)t * HD + h] = o;
}

extern "C" void kernel_launch(void* const* d_in, const int* in_sizes, int n_in,
                              void* d_out, int out_size, void* d_ws, size_t ws_size,
                              hipStream_t stream) {
    (void)in_sizes; (void)n_in; (void)out_size;
    const void* X   = d_in[0];
    const int*  idx = (const int*)d_in[1];
    const void* wts = d_in[2];
    const void* W1  = d_in[3];
    const void* W2  = d_in[4];
    float* out = (float*)d_out;

    char* ws = (char*)d_ws;
    int* flags = (int*)ws;                             // 128 B reserved
    int* cnt   = (int*)(ws + 128);                     // 128 B
    int* tok   = (int*)(ws + 256);                     // 32*768*4   = 98304 B
    int* smap  = (int*)(ws + 256 + 98304);             // 16384*4    = 65536 B
    unsigned short* mid = (unsigned short*)(ws + 164224);            // 25165824 B

    // new-path layout (lifetime-aliased): ybuf reuses W1b region after gemm1
    const size_t MIDE = 164224ull + 25165824ull;       // 25330048
    const size_t W2BO = MIDE;                          // +33554432 -> 58884480
    const size_t XBO  = W2BO + 33554432ull;            // +8388608  -> 67273088
    const size_t W1BO = XBO + 8388608ull;              // +67108864 -> 134381952
    const size_t NEED = W1BO + 67108864ull;

    hipMemsetAsync(ws, 0, 256, stream);  // flags + cnt
    detect_k<<<dim3(1), dim3(256), 0, stream>>>(X, idx, flags);
    route_k<<<dim3(64), dim3(256), 0, stream>>>(idx, flags, cnt, tok, smap);

    if (ws_size >= NEED) {
        unsigned short* W2b  = (unsigned short*)(ws + W2BO);
        unsigned short* Xb   = (unsigned short*)(ws + XBO);
        unsigned short* W1b  = (unsigned short*)(ws + W1BO);
        unsigned short* ybuf = (unsigned short*)(ws + W1BO);  // alias: W1b dead after gemm1
        convert_k<<<dim3(2048), dim3(256), 0, stream>>>(X, W1, W2, flags, Xb, W1b, W2b);
        gemm1n_k<<<dim3(6, 4, 32), dim3(256), 0, stream>>>(Xb, W1b, cnt, tok, mid);
        gemm2n_k<<<dim3(6, 8, 32), dim3(256), 0, stream>>>(mid, W2b, cnt, ybuf);
        gather_k<<<dim3(4096), dim3(256), 0, stream>>>(X, idx, wts, flags, smap, ybuf, out);
    } else {
        unsigned short* ybuf = (unsigned short*)(ws + 164224 + 25165824);
        gemm1_k<<<dim3(6, 4, 32), dim3(256), 0, stream>>>(X, W1, flags, cnt, tok, mid);
        gemm2_k<<<dim3(6, 8, 32), dim3(256), 0, stream>>>(mid, W2, flags, cnt, ybuf);
        gather_k<<<dim3(4096), dim3(256), 0, stream>>>(X, idx, wts, flags, smap, ybuf, out);
    }
}